// Round 9
// baseline (540.371 us; speedup 1.0000x reference)
//
#include <hip/hip_runtime.h>
#include <math.h>

typedef unsigned short u16t;
typedef __bf16 bf16x8 __attribute__((ext_vector_type(8)));
typedef float f32x4 __attribute__((ext_vector_type(4)));

#define MFMA16(a,b,c) __builtin_amdgcn_mfma_f32_16x16x32_bf16(a,b,c,0,0,0)

static constexpr float NEGBIG = -4294967295.0f;

__device__ __forceinline__ void split2(float x, u16t& h, u16t& l){
  __bf16 hb = (__bf16)x; float hf = (float)hb; __bf16 lb = (__bf16)(x - hf);
  h = __builtin_bit_cast(u16t, hb); l = __builtin_bit_cast(u16t, lb);
}
__device__ __forceinline__ u16t f2bfu(float x){
  __bf16 b = (__bf16)x; return __builtin_bit_cast(u16t, b);
}
// global -> LDS direct (16B per lane; LDS dest = wave-uniform base + lane*16)
__device__ __forceinline__ void gld16(void* l, const void* g){
  __builtin_amdgcn_global_load_lds(
      (const __attribute__((address_space(1))) unsigned int*)g,
      (__attribute__((address_space(3))) unsigned int*)l, 16, 0, 0);
}

// ---------------- K0: positional tables (double precision to match numpy) ----
__global__ void kpos(const float* __restrict__ vv, float* __restrict__ posS,
                     float* __restrict__ posbias){
  int t = blockIdx.x, h = threadIdx.x;
  double scale = exp((double)h * (-log(10000.0) / 255.0));
  double ang = (double)(t - 50) * scale;
  float sn = (float)sin(ang), cs = (float)cos(ang);
  posS[t*256 + h] = sn + cs;
  float contrib = sn*vv[h] + cs*vv[256 + h];
  for(int m = 32; m >= 1; m >>= 1) contrib += __shfl_xor(contrib, m, 64);
  __shared__ float red[4];
  if((threadIdx.x & 63) == 0) red[threadIdx.x >> 6] = contrib;
  __syncthreads();
  if(threadIdx.x == 0) posbias[t] = red[0]+red[1]+red[2]+red[3];
}

// ---------------- KW: transpose+split weights -> Wt[n][k] hi/lo bf16 --------
__global__ void kw(const float* __restrict__ Wq, const float* __restrict__ Wv,
                   u16t* __restrict__ Wth, u16t* __restrict__ Wtl){
  __shared__ float tile[16][17];
  int k0 = blockIdx.x * 16, n0 = blockIdx.y * 16;
  int tx = threadIdx.x & 15, ty = threadIdx.x >> 4;
  int n = n0 + tx, k = k0 + ty;
  float val = (n < 256) ? Wq[k*256 + n] : Wv[k*256 + (n - 256)];
  tile[ty][tx] = val;
  __syncthreads();
  float v2 = tile[tx][ty];                 // = W[k0+tx][n0+ty]
  u16t h, l; split2(v2, h, l);
  size_t idx = (size_t)(n0 + ty) * 512 + k0 + tx;
  Wth[idx] = h; Wtl[idx] = l;
}

// ---------------- K1: prep — wave-per-row, float4 vectorized ----------------
__global__ __launch_bounds__(256) void kprep(const float* __restrict__ X,
                      const int* __restrict__ masks,
                      const float* __restrict__ u, const float* __restrict__ posS,
                      const float* __restrict__ posbias, float* __restrict__ out,
                      u16t* __restrict__ KKh, u16t* __restrict__ KKl,
                      u16t* __restrict__ Xh, u16t* __restrict__ Xl,
                      float* __restrict__ biasArr, int doSplit){
  int wave = threadIdx.x >> 6, lane = threadIdx.x & 63;
  int r = blockIdx.x*4 + wave;
  int b = r / 100, t = r - b*100;
  size_t xb = (size_t)r * 512;
  int c = lane*4;
  float4 x1 = *(const float4*)(X + xb + c);
  float4 x2 = *(const float4*)(X + xb + 256 + c);
  size_t ob = (size_t)r * 768;
  *(float4*)(out + ob + c) = x1;
  *(float4*)(out + ob + 256 + c) = x2;
  float4 ps = *(const float4*)(posS + t*256 + c);
  u16t kh[4], kl[4];
  split2(x1.x + x2.x + ps.x, kh[0], kl[0]);
  split2(x1.y + x2.y + ps.y, kh[1], kl[1]);
  split2(x1.z + x2.z + ps.z, kh[2], kl[2]);
  split2(x1.w + x2.w + ps.w, kh[3], kl[3]);
  uint2 khv = { (unsigned)kh[0] | ((unsigned)kh[1]<<16),
                (unsigned)kh[2] | ((unsigned)kh[3]<<16) };
  uint2 klv = { (unsigned)kl[0] | ((unsigned)kl[1]<<16),
                (unsigned)kl[2] | ((unsigned)kl[3]<<16) };
  *(uint2*)(KKh + (size_t)r*256 + c) = khv;
  *(uint2*)(KKl + (size_t)r*256 + c) = klv;
  if(doSplit){
    u16t h4[4], l4[4];
    split2(x1.x, h4[0], l4[0]); split2(x1.y, h4[1], l4[1]);
    split2(x1.z, h4[2], l4[2]); split2(x1.w, h4[3], l4[3]);
    uint2 hv = { (unsigned)h4[0] | ((unsigned)h4[1]<<16),
                 (unsigned)h4[2] | ((unsigned)h4[3]<<16) };
    uint2 lv = { (unsigned)l4[0] | ((unsigned)l4[1]<<16),
                 (unsigned)l4[2] | ((unsigned)l4[3]<<16) };
    *(uint2*)(Xh + xb + c) = hv;
    *(uint2*)(Xl + xb + c) = lv;
    split2(x2.x, h4[0], l4[0]); split2(x2.y, h4[1], l4[1]);
    split2(x2.z, h4[2], l4[2]); split2(x2.w, h4[3], l4[3]);
    uint2 hv2 = { (unsigned)h4[0] | ((unsigned)h4[1]<<16),
                  (unsigned)h4[2] | ((unsigned)h4[3]<<16) };
    uint2 lv2 = { (unsigned)l4[0] | ((unsigned)l4[1]<<16),
                  (unsigned)l4[2] | ((unsigned)l4[3]<<16) };
    *(uint2*)(Xh + xb + 256 + c) = hv2;
    *(uint2*)(Xl + xb + 256 + c) = lv2;
  }
  float4 u1 = *(const float4*)(u + c);
  float4 u2 = *(const float4*)(u + 256 + c);
  float contrib = x1.x*u1.x + x1.y*u1.y + x1.z*u1.z + x1.w*u1.w
                + x2.x*u2.x + x2.y*u2.y + x2.z*u2.z + x2.w*u2.w;
  for(int m = 32; m >= 1; m >>= 1) contrib += __shfl_xor(contrib, m, 64);
  if(lane == 0)
    biasArr[b*112 + t] = contrib + posbias[t] + (float)masks[r] * NEGBIG;
}

// ---------------- K2a: bf16 GEMM, 256x256 tile, 8 waves, 128KB LDS ----------
// Same validated staging/read algebra as the 128-tile version (wave stages 32
// rows, source-XOR swizzle, linear global_load_lds dest); 4x the MFMA work per
// barrier. Waves 2M x 4N, per-wave 128x64 output, acc[8][4].
__global__ __launch_bounds__(512, 1) void kgemm_bf(const u16t* __restrict__ Xh,
                      const u16t* __restrict__ Xl,
                      const u16t* __restrict__ Wth, const u16t* __restrict__ Wtl,
                      u16t* __restrict__ Qh, u16t* __restrict__ Ql,
                      u16t* __restrict__ Vt){
  extern __shared__ char smem[];
  char* Ah = smem;              // [256][128B] bf16, swizzled-effective, 32KB
  char* Al = smem + 32768;
  char* Bh = smem + 65536;
  char* Bl = smem + 98304;
  int bid = blockIdx.x;
  int logical = (bid & 7)*100 + (bid >> 3);   // XCD-chunked (800 % 8 == 0)
  int nb = logical & 1, mb = logical >> 1;    // nb fast -> A panel L2 reuse
  bool isQ = (nb == 0);
  int row0 = mb * 256, n0b = nb * 256;        // n0b = row base in Wt
  int tid = threadIdx.x, lane = tid & 63, wave = tid >> 6;
  int wr = (wave >> 2) * 128, wc = (wave & 3) * 64;
  f32x4 acc[8][4];
  #pragma unroll
  for(int i=0;i<8;i++)
    #pragma unroll
    for(int j=0;j<4;j++) acc[i][j] = (f32x4){0.f,0.f,0.f,0.f};

  // staging: wave w stages rows w*32..w*32+31 of each 256x64 tile,
  // 4 issues of 8 rows. LDS row r, chunk (lane&7) holds global chunk
  // (lane&7)^(r&7); r&7 == lane>>3  =>  source chunk = (lane&7)^(lane>>3).
  int arow = wave*32 + (lane >> 3);
  int acol = ((lane & 7) ^ (lane >> 3)) * 8;      // pre-swizzled source col
  const u16t* gAh = Xh  + (size_t)(row0 + arow)*512 + acol;
  const u16t* gAl = Xl  + (size_t)(row0 + arow)*512 + acol;
  const u16t* gBh = Wth + (size_t)(n0b  + arow)*512 + acol;
  const u16t* gBl = Wtl + (size_t)(n0b  + arow)*512 + acol;
  char* lAh = Ah + wave*4096;
  char* lAl = Al + wave*4096;
  char* lBh = Bh + wave*4096;
  char* lBl = Bl + wave*4096;

  for(int kt = 0; kt < 8; kt++){
    int k0 = kt * 64;
    #pragma unroll
    for(int q = 0; q < 4; q++){
      gld16(lAh + q*1024, gAh + (size_t)q*8*512 + k0);
      gld16(lBh + q*1024, gBh + (size_t)q*8*512 + k0);
    }
    if(isQ){
      #pragma unroll
      for(int q = 0; q < 4; q++){
        gld16(lAl + q*1024, gAl + (size_t)q*8*512 + k0);
        gld16(lBl + q*1024, gBl + (size_t)q*8*512 + k0);
      }
    }
    __syncthreads();
    #pragma unroll
    for(int kk = 0; kk < 2; kk++){
      int kb = kk*64 + (lane >> 4)*16;            // byte offset within 128B row
      bf16x8 bh[4], bl[4];
      #pragma unroll
      for(int j = 0; j < 4; j++){
        int nr = wc + j*16 + (lane & 15);
        int by = kb ^ ((nr & 7) << 4);
        bh[j] = *(bf16x8*)(Bh + nr*128 + by);
        if(isQ) bl[j] = *(bf16x8*)(Bl + nr*128 + by);
      }
      #pragma unroll
      for(int i = 0; i < 8; i++){
        int rr = wr + i*16 + (lane & 15);
        int by = kb ^ ((rr & 7) << 4);
        bf16x8 ah = *(bf16x8*)(Ah + rr*128 + by);
        if(isQ){
          bf16x8 al = *(bf16x8*)(Al + rr*128 + by);
          #pragma unroll
          for(int j = 0; j < 4; j++){
            acc[i][j] = MFMA16(ah, bh[j], acc[i][j]);
            acc[i][j] = MFMA16(ah, bl[j], acc[i][j]);
            acc[i][j] = MFMA16(al, bh[j], acc[i][j]);
          }
        } else {
          #pragma unroll
          for(int j = 0; j < 4; j++)
            acc[i][j] = MFMA16(ah, bh[j], acc[i][j]);
        }
      }
    }
    __syncthreads();
  }
  // epilogue
  #pragma unroll
  for(int i = 0; i < 8; i++)
    #pragma unroll
    for(int j = 0; j < 4; j++){
      int colBase = wc + j*16 + (lane & 15);
      #pragma unroll
      for(int rg = 0; rg < 4; rg++){
        int row = row0 + wr + i*16 + ((lane >> 4) << 2) + rg;
        float val = acc[i][j][rg];
        if(isQ){
          u16t qh_, ql_; split2(val, qh_, ql_);
          size_t idx = (size_t)row*256 + colBase;
          Qh[idx] = qh_; Ql[idx] = ql_;
        } else {
          int bb = row / 100; int tt = row - bb*100;
          Vt[((size_t)(bb*256 + colBase))*112 + tt] = f2bfu(val);
        }
      }
    }
}

// ---------------- K2b: fp32-A GEMM (fallback, round-4 validated) ------------
__global__ __launch_bounds__(256) void kgemm_f32(const float* __restrict__ X,
                      const u16t* __restrict__ Wth, const u16t* __restrict__ Wtl,
                      u16t* __restrict__ Qh, u16t* __restrict__ Ql,
                      u16t* __restrict__ Vt){
  extern __shared__ char smem[];
  char* Af = smem;             // [128 rows][256B] fp32, swizzled blocks, 32KB
  char* Bh = smem + 32768;     // [128 rows][128B] bf16, swizzled blocks, 16KB
  char* Bl = smem + 49152;
  int bid = blockIdx.x;
  int logical = (bid & 7)*400 + (bid >> 3);
  int nb = logical & 3, mb = logical >> 2;
  bool isQ = (nb < 2);
  int row0 = mb * 128, n0 = nb * 128;
  int tid = threadIdx.x, lane = tid & 63, wave = tid >> 6;
  int wr = (wave >> 1) * 64, wc = (wave & 1) * 64;
  int lr = lane >> 4, lb = lane & 15;
  f32x4 acc[4][4];
  #pragma unroll
  for(int i=0;i<4;i++)
    #pragma unroll
    for(int j=0;j<4;j++) acc[i][j] = (f32x4){0.f,0.f,0.f,0.f};

  int brow = wave*32 + (lane >> 3);
  int bcol = ((lane & 7) ^ (lane >> 3)) * 8;
  const u16t* gBh = Wth + (size_t)(n0 + brow)*512 + bcol;
  const u16t* gBl = Wtl + (size_t)(n0 + brow)*512 + bcol;
  char* lBh = Bh + wave*4096;
  char* lBl = Bl + wave*4096;
  const float* gA = X + (size_t)(row0 + wave*32 + lr)*512;
  int ac[4];
  #pragma unroll
  for(int qm = 0; qm < 4; qm++) ac[qm] = (lb ^ (lr + qm*4)) * 4;
  char* lAf = Af + wave*8192;

  for(int kt = 0; kt < 8; kt++){
    int k0 = kt * 64;
    #pragma unroll
    for(int q = 0; q < 8; q++)
      gld16(lAf + q*1024, gA + (size_t)q*4*512 + k0 + ac[q&3]);
    #pragma unroll
    for(int q = 0; q < 4; q++){
      gld16(lBh + q*1024, gBh + (size_t)q*8*512 + k0);
      if(isQ) gld16(lBl + q*1024, gBl + (size_t)q*8*512 + k0);
    }
    __syncthreads();
    #pragma unroll
    for(int kk = 0; kk < 2; kk++){
      bf16x8 ah[4], al[4], bh[4], bl[4];
      #pragma unroll
      for(int i = 0; i < 4; i++){
        int rr = wr + i*16 + lb;
        int g = kk*8 + lr*2;
        float4 x0 = *(float4*)(Af + rr*256 + ((g    ) ^ lb)*16);
        float4 x1 = *(float4*)(Af + rr*256 + ((g + 1) ^ lb)*16);
        float xs[8] = {x0.x,x0.y,x0.z,x0.w,x1.x,x1.y,x1.z,x1.w};
        #pragma unroll
        for(int e = 0; e < 8; e++){
          __bf16 hb = (__bf16)xs[e];
          ah[i][e] = hb;
          if(isQ) al[i][e] = (__bf16)(xs[e] - (float)hb);
        }
      }
      int kb = kk*64 + lr*16;
      #pragma unroll
      for(int j = 0; j < 4; j++){
        int nr = wc + j*16 + lb;
        int by = kb ^ ((nr & 7) << 4);
        bh[j] = *(bf16x8*)(Bh + nr*128 + by);
        if(isQ) bl[j] = *(bf16x8*)(Bl + nr*128 + by);
      }
      #pragma unroll
      for(int i = 0; i < 4; i++)
        #pragma unroll
        for(int j = 0; j < 4; j++){
          acc[i][j] = MFMA16(ah[i], bh[j], acc[i][j]);
          if(isQ){
            acc[i][j] = MFMA16(ah[i], bl[j], acc[i][j]);
            acc[i][j] = MFMA16(al[i], bh[j], acc[i][j]);
          }
        }
    }
    __syncthreads();
  }
  #pragma unroll
  for(int i = 0; i < 4; i++)
    #pragma unroll
    for(int j = 0; j < 4; j++){
      int colBase = wc + j*16 + lb;
      #pragma unroll
      for(int rg = 0; rg < 4; rg++){
        int row = row0 + wr + i*16 + (lr << 2) + rg;
        float val = acc[i][j][rg];
        if(isQ){
          u16t qh_, ql_; split2(val, qh_, ql_);
          size_t idx = (size_t)row*256 + (n0 + colBase);
          Qh[idx] = qh_; Ql[idx] = ql_;
        } else {
          int bb = row / 100; int tt = row - bb*100;
          int hcol = (n0 - 256) + colBase;
          Vt[((size_t)(bb*256 + hcol))*112 + tt] = f2bfu(val);
        }
      }
    }
}

// ---------------- K3: attention per batch, chunked staging (64KB LDS) -------
__global__ __launch_bounds__(256) void kattn(const u16t* __restrict__ Qh,
                      const u16t* __restrict__ Ql, const u16t* __restrict__ KKh,
                      const u16t* __restrict__ KKl, const u16t* __restrict__ Vt,
                      const float* __restrict__ biasArr, float* __restrict__ out){
  extern __shared__ char smem[];
  char* KH = smem;            // phase1: chunk [64][512B] swz, 32KB
  char* KL = smem + 32768;
  char* P  = smem;            // phase2: [112][256B] swz, 28672
  char* V  = smem + 28672;    // phase2: chunk [128][256B] swz, 32KB
  int b = blockIdx.x, tid = threadIdx.x, lane = tid & 63, wave = tid >> 6;

  float sc[2][7][4];

  // ---- QK^T over two K chunks ----
  for(int c = 0; c < 2; c++){
    if(c) __syncthreads();            // chunk0 reads done before restage
    int rows = c ? 48 : 64;
    for(int it = 0; it < 8; it++){
      int idx = it*256 + tid;
      if(idx < rows*32){
        int tl = idx >> 5, seg = idx & 31;
        int t = tl + c*64;
        int byte = (seg*16) ^ ((tl & 7) << 4);
        uint4 hv = {0,0,0,0}, lv = {0,0,0,0};
        if(t < 100){
          size_t g = (size_t)(b*100 + t)*256 + seg*8;
          hv = *(const uint4*)(KKh + g);
          lv = *(const uint4*)(KKl + g);
        }
        *(uint4*)(KH + tl*512 + byte) = hv;
        *(uint4*)(KL + tl*512 + byte) = lv;
      }
    }
    __syncthreads();
    int tcA = c ? 4 : 0, tcB = c ? 7 : 4;
    for(int uu = 0; uu < 2; uu++){
      if(uu == 1 && wave >= 3) continue;
      int tr = (uu == 0) ? wave : wave + 4;
      int s = tr*16 + (lane & 15);
      int gs = (s > 99) ? 99 : s;
      size_t qbase = (size_t)(b*100 + gs)*256 + (lane >> 4)*8;
      bf16x8 qh[8], ql[8];
      #pragma unroll
      for(int ks = 0; ks < 8; ks++){
        qh[ks] = *(const bf16x8*)(Qh + qbase + ks*32);
        ql[ks] = *(const bf16x8*)(Ql + qbase + ks*32);
      }
      for(int tc = tcA; tc < tcB; tc++){
        f32x4 a = (f32x4){0.f,0.f,0.f,0.f};
        int tl = tc*16 + (lane & 15) - c*64;     // local row in chunk
        #pragma unroll
        for(int ks = 0; ks < 8; ks++){
          int kb = ks*64 + (lane >> 4)*16;
          int by = kb ^ ((tl & 7) << 4);
          bf16x8 bh = *(bf16x8*)(KH + tl*512 + by);
          bf16x8 bl = *(bf16x8*)(KL + tl*512 + by);
          a = MFMA16(qh[ks], bh, a);
          a = MFMA16(qh[ks], bl, a);
          a = MFMA16(ql[ks], bh, a);
        }
        int t = tc*16 + (lane & 15);
        float bb = (t < 100) ? biasArr[b*112 + t] : -INFINITY;
        #pragma unroll
        for(int r = 0; r < 4; r++) sc[uu][tc][r] = a[r] + bb;
      }
    }
  }

  // ---- softmax (regs + 16-lane-group shuffles) ----
  #pragma unroll
  for(int uu = 0; uu < 2; uu++){
    if(uu == 1 && wave >= 3) continue;
    #pragma unroll
    for(int r = 0; r < 4; r++){
      float m = sc[uu][0][r];
      #pragma unroll
      for(int tc = 1; tc < 7; tc++) m = fmaxf(m, sc[uu][tc][r]);
      for(int msk = 8; msk >= 1; msk >>= 1) m = fmaxf(m, __shfl_xor(m, msk, 64));
      float ssum = 0.f;
      #pragma unroll
      for(int tc = 0; tc < 7; tc++){
        float p = expf(sc[uu][tc][r] - m);
        sc[uu][tc][r] = p; ssum += p;
      }
      for(int msk = 8; msk >= 1; msk >>= 1) ssum += __shfl_xor(ssum, msk, 64);
      float inv = 1.0f / ssum;
      #pragma unroll
      for(int tc = 0; tc < 7; tc++) sc[uu][tc][r] *= inv;
    }
  }
  __syncthreads();   // all K reads done; safe to overwrite with P/V

  // ---- write P (bf16, swizzled) + zero pad cols ----
  #pragma unroll
  for(int uu = 0; uu < 2; uu++){
    if(uu == 1 && wave >= 3) continue;
    int tr = (uu == 0) ? wave : wave + 4;
    #pragma unroll
    for(int tc = 0; tc < 7; tc++)
      #pragma unroll
      for(int r = 0; r < 4; r++){
        int srow = tr*16 + ((lane >> 4) << 2) + r;
        int t = tc*16 + (lane & 15);
        *(u16t*)(P + srow*256 + ((t*2) ^ ((srow & 7) << 4))) = f2bfu(sc[uu][tc][r]);
      }
  }
  for(int idx = tid; idx < 112*16; idx += 256){
    int srow = idx >> 4; int t = 112 + (idx & 15);
    *(u16t*)(P + srow*256 + ((t*2) ^ ((srow & 7) << 4))) = 0;
  }

  // ---- PV over two V chunks of 128 h-rows each ----
  bf16x8 pa[4];
  for(int d = 0; d < 2; d++){
    if(d) __syncthreads();             // chunk0 reads done before restage
    for(int it = 0; it < 8; it++){
      int idx = it*256 + tid;          // 128 rows * 16 segs
      int hl = idx >> 4, s16 = idx & 15; int t0 = s16*8;
      int h = d*128 + hl;
      uint4 v = {0,0,0,0};
      if(t0 < 112) v = *(const uint4*)(Vt + ((size_t)(b*256 + h))*112 + t0);
      *(uint4*)(V + hl*256 + ((t0*2) ^ ((hl & 7) << 4))) = v;
    }
    __syncthreads();
    #pragma unroll
    for(int uu = 0; uu < 2; uu++){
      if(uu == 1 && wave >= 3) continue;
      int tr = (uu == 0) ? wave : wave + 4;
      int srow = tr*16 + (lane & 15);
      #pragma unroll
      for(int ks = 0; ks < 4; ks++){
        int kb = ks*64 + (lane >> 4)*16;
        pa[ks] = *(bf16x8*)(P + srow*256 + (kb ^ ((srow & 7) << 4)));
      }
      #pragma unroll
      for(int tcl = 0; tcl < 8; tcl++){
        int tc = d*8 + tcl;
        int hl = tcl*16 + (lane & 15);       // local V row
        f32x4 a = (f32x4){0.f,0.f,0.f,0.f};
        #pragma unroll
        for(int ks = 0; ks < 4; ks++){
          int kb = ks*64 + (lane >> 4)*16;
          bf16x8 vb = *(bf16x8*)(V + hl*256 + (kb ^ ((hl & 7) << 4)));
          a = MFMA16(pa[ks], vb, a);
        }
        #pragma unroll
        for(int r = 0; r < 4; r++){
          int so = tr*16 + ((lane >> 4) << 2) + r;
          if(so < 100)
            out[((size_t)(b*100 + so))*768 + 512 + tc*16 + (lane & 15)] = a[r];
        }
      }
    }
  }
}

extern "C" void kernel_launch(void* const* d_in, const int* in_sizes, int n_in,
                              void* d_out, int out_size, void* d_ws, size_t ws_size,
                              hipStream_t stream) {
  const float* X     = (const float*)d_in[0];
  const int*   masks = (const int*)d_in[1];
  const float* Wq    = (const float*)d_in[2];
  const float* Wv    = (const float*)d_in[3];
  const float* u     = (const float*)d_in[4];
  const float* v     = (const float*)d_in[5];
  float* out = (float*)d_out;
  char* ws = (char*)d_ws;

  // Big layout needs Xh/Xl (100 MB each).
  const size_t NEED_BIG = 479760896ULL;
  bool big = (ws_size >= NEED_BIG);

  size_t o = 0;
  auto alloc = [&](size_t n){ size_t r = o; o += (n + 255) & ~(size_t)255; return r; };
  u16t*  Qh      = (u16t*)(ws + alloc(52428800));    // 102400 x 256 bf16
  u16t*  Ql      = (u16t*)(ws + alloc(52428800));
  u16t*  KKh     = (u16t*)(ws + alloc(52428800));
  u16t*  KKl     = (u16t*)(ws + alloc(52428800));
  u16t*  Vt      = (u16t*)(ws + alloc(58720256));    // 1024 x 256 x 112 bf16
  u16t*  Wth     = (u16t*)(ws + alloc(524288));      // 512 x 512 bf16
  u16t*  Wtl     = (u16t*)(ws + alloc(524288));
  float* posS    = (float*)(ws + alloc(102400));     // 100 x 256 f32
  float* posbias = (float*)(ws + alloc(512));        // 100 f32
  float* biasArr = (float*)(ws + alloc(458752));     // 1024 x 112 f32
  u16t*  Xh      = nullptr; u16t* Xl = nullptr;
  if(big){
    Xh = (u16t*)(ws + alloc(104857600));             // 102400 x 512 bf16
    Xl = (u16t*)(ws + alloc(104857600));
  }

  hipFuncSetAttribute((const void*)kgemm_bf,  hipFuncAttributeMaxDynamicSharedMemorySize, 131072);
  hipFuncSetAttribute((const void*)kgemm_f32, hipFuncAttributeMaxDynamicSharedMemorySize, 65536);
  hipFuncSetAttribute((const void*)kattn,     hipFuncAttributeMaxDynamicSharedMemorySize, 65536);

  kpos<<<100, 256, 0, stream>>>(v, posS, posbias);
  kw<<<dim3(32, 32), 256, 0, stream>>>(Wq, Wv, Wth, Wtl);
  kprep<<<25600, 256, 0, stream>>>(X, masks, u, posS, posbias, out, KKh, KKl,
                                   Xh, Xl, biasArr, big ? 1 : 0);
  if(big)
    kgemm_bf<<<800, 512, 131072, stream>>>(Xh, Xl, Wth, Wtl, Qh, Ql, Vt);
  else
    kgemm_f32<<<3200, 256, 65536, stream>>>(X, Wth, Wtl, Qh, Ql, Vt);
  kattn<<<1024, 256, 65536, stream>>>(Qh, Ql, KKh, KKl, Vt, biasArr, out);
}

// Round 10
// 437.915 us; speedup vs baseline: 1.2340x; 1.2340x over previous
//
#include <hip/hip_runtime.h>
#include <math.h>

typedef unsigned short u16t;
typedef __bf16 bf16x8 __attribute__((ext_vector_type(8)));
typedef float f32x4 __attribute__((ext_vector_type(4)));

#define MFMA16(a,b,c) __builtin_amdgcn_mfma_f32_16x16x32_bf16(a,b,c,0,0,0)

static constexpr float NEGBIG = -4294967295.0f;

__device__ __forceinline__ void split2(float x, u16t& h, u16t& l){
  __bf16 hb = (__bf16)x; float hf = (float)hb; __bf16 lb = (__bf16)(x - hf);
  h = __builtin_bit_cast(u16t, hb); l = __builtin_bit_cast(u16t, lb);
}
__device__ __forceinline__ u16t f2bfu(float x){
  __bf16 b = (__bf16)x; return __builtin_bit_cast(u16t, b);
}
// global -> LDS direct (16B per lane; LDS dest = wave-uniform base + lane*16)
__device__ __forceinline__ void gld16(void* l, const void* g){
  __builtin_amdgcn_global_load_lds(
      (const __attribute__((address_space(1))) unsigned int*)g,
      (__attribute__((address_space(3))) unsigned int*)l, 16, 0, 0);
}

// ---------------- K0: pos tables (blocks 0..99) + weight transpose (100..1123)
__global__ void kposw(const float* __restrict__ vv,
                      const float* __restrict__ Wq, const float* __restrict__ Wv,
                      float* __restrict__ posS, float* __restrict__ posbias,
                      u16t* __restrict__ Wth, u16t* __restrict__ Wtl){
  __shared__ float red[4];
  __shared__ float tile[16][17];
  int bid = blockIdx.x;
  if(bid < 100){
    int t = bid, h = threadIdx.x;
    double scale = exp((double)h * (-log(10000.0) / 255.0));
    double ang = (double)(t - 50) * scale;
    float sn = (float)sin(ang), cs = (float)cos(ang);
    posS[t*256 + h] = sn + cs;
    float contrib = sn*vv[h] + cs*vv[256 + h];
    for(int m = 32; m >= 1; m >>= 1) contrib += __shfl_xor(contrib, m, 64);
    if((threadIdx.x & 63) == 0) red[threadIdx.x >> 6] = contrib;
    __syncthreads();
    if(threadIdx.x == 0) posbias[t] = red[0]+red[1]+red[2]+red[3];
  } else {
    int wb = bid - 100;
    int k0 = (wb & 31) * 16, n0 = (wb >> 5) * 16;
    int tx = threadIdx.x & 15, ty = threadIdx.x >> 4;
    int n = n0 + tx, k = k0 + ty;
    float val = (n < 256) ? Wq[k*256 + n] : Wv[k*256 + (n - 256)];
    tile[ty][tx] = val;
    __syncthreads();
    float v2 = tile[tx][ty];                 // = W[k0+tx][n0+ty]
    u16t h, l; split2(v2, h, l);
    size_t idx = (size_t)(n0 + ty) * 512 + k0 + tx;
    Wth[idx] = h; Wtl[idx] = l;
  }
}

// ---------------- K1: prep — wave-per-row, float4 vectorized ----------------
__global__ __launch_bounds__(256) void kprep(const float* __restrict__ X,
                      const int* __restrict__ masks,
                      const float* __restrict__ u, const float* __restrict__ posS,
                      const float* __restrict__ posbias, float* __restrict__ out,
                      u16t* __restrict__ KKh, u16t* __restrict__ KKl,
                      u16t* __restrict__ Xh, u16t* __restrict__ Xl,
                      float* __restrict__ biasArr, int doSplit){
  int wave = threadIdx.x >> 6, lane = threadIdx.x & 63;
  int r = blockIdx.x*4 + wave;
  int b = r / 100, t = r - b*100;
  size_t xb = (size_t)r * 512;
  int c = lane*4;
  float4 x1 = *(const float4*)(X + xb + c);
  float4 x2 = *(const float4*)(X + xb + 256 + c);
  size_t ob = (size_t)r * 768;
  *(float4*)(out + ob + c) = x1;
  *(float4*)(out + ob + 256 + c) = x2;
  float4 ps = *(const float4*)(posS + t*256 + c);
  u16t kh[4], kl[4];
  split2(x1.x + x2.x + ps.x, kh[0], kl[0]);
  split2(x1.y + x2.y + ps.y, kh[1], kl[1]);
  split2(x1.z + x2.z + ps.z, kh[2], kl[2]);
  split2(x1.w + x2.w + ps.w, kh[3], kl[3]);
  uint2 khv = { (unsigned)kh[0] | ((unsigned)kh[1]<<16),
                (unsigned)kh[2] | ((unsigned)kh[3]<<16) };
  uint2 klv = { (unsigned)kl[0] | ((unsigned)kl[1]<<16),
                (unsigned)kl[2] | ((unsigned)kl[3]<<16) };
  *(uint2*)(KKh + (size_t)r*256 + c) = khv;
  *(uint2*)(KKl + (size_t)r*256 + c) = klv;
  if(doSplit){
    u16t h4[4], l4[4];
    split2(x1.x, h4[0], l4[0]); split2(x1.y, h4[1], l4[1]);
    split2(x1.z, h4[2], l4[2]); split2(x1.w, h4[3], l4[3]);
    uint2 hv = { (unsigned)h4[0] | ((unsigned)h4[1]<<16),
                 (unsigned)h4[2] | ((unsigned)h4[3]<<16) };
    uint2 lv = { (unsigned)l4[0] | ((unsigned)l4[1]<<16),
                 (unsigned)l4[2] | ((unsigned)l4[3]<<16) };
    *(uint2*)(Xh + xb + c) = hv;
    *(uint2*)(Xl + xb + c) = lv;
    split2(x2.x, h4[0], l4[0]); split2(x2.y, h4[1], l4[1]);
    split2(x2.z, h4[2], l4[2]); split2(x2.w, h4[3], l4[3]);
    uint2 hv2 = { (unsigned)h4[0] | ((unsigned)h4[1]<<16),
                  (unsigned)h4[2] | ((unsigned)h4[3]<<16) };
    uint2 lv2 = { (unsigned)l4[0] | ((unsigned)l4[1]<<16),
                  (unsigned)l4[2] | ((unsigned)l4[3]<<16) };
    *(uint2*)(Xh + xb + 256 + c) = hv2;
    *(uint2*)(Xl + xb + 256 + c) = lv2;
  }
  float4 u1 = *(const float4*)(u + c);
  float4 u2 = *(const float4*)(u + 256 + c);
  float contrib = x1.x*u1.x + x1.y*u1.y + x1.z*u1.z + x1.w*u1.w
                + x2.x*u2.x + x2.y*u2.y + x2.z*u2.z + x2.w*u2.w;
  for(int m = 32; m >= 1; m >>= 1) contrib += __shfl_xor(contrib, m, 64);
  if(lane == 0)
    biasArr[b*112 + t] = contrib + posbias[t] + (float)masks[r] * NEGBIG;
}

// ---------------- K2a: pure-bf16 GEMM (round-5/8 proven, ~213us) -------------
__global__ __launch_bounds__(256) void kgemm_bf(const u16t* __restrict__ Xh,
                      const u16t* __restrict__ Xl,
                      const u16t* __restrict__ Wth, const u16t* __restrict__ Wtl,
                      u16t* __restrict__ Qh, u16t* __restrict__ Ql,
                      u16t* __restrict__ Vt){
  extern __shared__ char smem[];
  char* Ah = smem;             // [128][64] bf16, swizzled-effective, 16KB
  char* Al = smem + 16384;
  char* Bh = smem + 32768;
  char* Bl = smem + 49152;
  int bid = blockIdx.x;
  int logical = (bid & 7)*400 + (bid >> 3);   // XCD-chunked (3200 % 8 == 0)
  int nb = logical & 3, mb = logical >> 2;    // nb fast -> A panel L2 reuse
  bool isQ = (nb < 2);
  int row0 = mb * 128, n0 = nb * 128;
  int tid = threadIdx.x, lane = tid & 63, wave = tid >> 6;
  int wr = (wave >> 1) * 64, wc = (wave & 1) * 64;
  f32x4 acc[4][4];
  #pragma unroll
  for(int i=0;i<4;i++)
    #pragma unroll
    for(int j=0;j<4;j++) acc[i][j] = (f32x4){0.f,0.f,0.f,0.f};

  // staging: wave w stages rows w*32..w*32+31, 4 issues of 8 rows each.
  // LDS row r, 16B-block (lane&7) holds global block (lane&7)^(r&7); r&7==lane>>3.
  int arow = wave*32 + (lane >> 3);
  int acol = ((lane & 7) ^ (lane >> 3)) * 8;      // pre-swizzled source col
  const u16t* gAh = Xh  + (size_t)(row0 + arow)*512 + acol;
  const u16t* gAl = Xl  + (size_t)(row0 + arow)*512 + acol;
  const u16t* gBh = Wth + (size_t)(n0  + arow)*512 + acol;
  const u16t* gBl = Wtl + (size_t)(n0  + arow)*512 + acol;
  char* lAh = Ah + wave*4096;
  char* lAl = Al + wave*4096;
  char* lBh = Bh + wave*4096;
  char* lBl = Bl + wave*4096;

  for(int kt = 0; kt < 8; kt++){
    int k0 = kt * 64;
    #pragma unroll
    for(int q = 0; q < 4; q++){
      gld16(lAh + q*1024, gAh + (size_t)q*8*512 + k0);
      gld16(lBh + q*1024, gBh + (size_t)q*8*512 + k0);
    }
    if(isQ){
      #pragma unroll
      for(int q = 0; q < 4; q++){
        gld16(lAl + q*1024, gAl + (size_t)q*8*512 + k0);
        gld16(lBl + q*1024, gBl + (size_t)q*8*512 + k0);
      }
    }
    __syncthreads();
    #pragma unroll
    for(int kk = 0; kk < 2; kk++){
      int kb = kk*64 + (lane >> 4)*16;            // byte offset within 128B row
      bf16x8 ah[4], al[4], bh[4], bl[4];
      #pragma unroll
      for(int i = 0; i < 4; i++){
        int rr = wr + i*16 + (lane & 15);
        int by = kb ^ ((rr & 7) << 4);
        ah[i] = *(bf16x8*)(Ah + rr*128 + by);
        if(isQ) al[i] = *(bf16x8*)(Al + rr*128 + by);
      }
      #pragma unroll
      for(int j = 0; j < 4; j++){
        int nr = wc + j*16 + (lane & 15);
        int by = kb ^ ((nr & 7) << 4);
        bh[j] = *(bf16x8*)(Bh + nr*128 + by);
        if(isQ) bl[j] = *(bf16x8*)(Bl + nr*128 + by);
      }
      #pragma unroll
      for(int i = 0; i < 4; i++)
        #pragma unroll
        for(int j = 0; j < 4; j++){
          acc[i][j] = MFMA16(ah[i], bh[j], acc[i][j]);
          if(isQ){
            acc[i][j] = MFMA16(ah[i], bl[j], acc[i][j]);
            acc[i][j] = MFMA16(al[i], bh[j], acc[i][j]);
          }
        }
    }
    __syncthreads();
  }
  // epilogue
  #pragma unroll
  for(int i = 0; i < 4; i++)
    #pragma unroll
    for(int j = 0; j < 4; j++){
      int colBase = wc + j*16 + (lane & 15);
      #pragma unroll
      for(int rg = 0; rg < 4; rg++){
        int row = row0 + wr + i*16 + ((lane >> 4) << 2) + rg;
        float val = acc[i][j][rg];
        if(isQ){
          u16t qh_, ql_; split2(val, qh_, ql_);
          size_t idx = (size_t)row*256 + (n0 + colBase);
          Qh[idx] = qh_; Ql[idx] = ql_;
        } else {
          int bb = row / 100; int tt = row - bb*100;
          int hcol = (n0 - 256) + colBase;
          Vt[((size_t)(bb*256 + hcol))*112 + tt] = f2bfu(val);
        }
      }
    }
}

// ---------------- K2b: fp32-A GEMM (fallback, round-4 validated) ------------
__global__ __launch_bounds__(256) void kgemm_f32(const float* __restrict__ X,
                      const u16t* __restrict__ Wth, const u16t* __restrict__ Wtl,
                      u16t* __restrict__ Qh, u16t* __restrict__ Ql,
                      u16t* __restrict__ Vt){
  extern __shared__ char smem[];
  char* Af = smem;             // [128 rows][256B] fp32, swizzled blocks, 32KB
  char* Bh = smem + 32768;     // [128 rows][128B] bf16, swizzled blocks, 16KB
  char* Bl = smem + 49152;
  int bid = blockIdx.x;
  int logical = (bid & 7)*400 + (bid >> 3);
  int nb = logical & 3, mb = logical >> 2;
  bool isQ = (nb < 2);
  int row0 = mb * 128, n0 = nb * 128;
  int tid = threadIdx.x, lane = tid & 63, wave = tid >> 6;
  int wr = (wave >> 1) * 64, wc = (wave & 1) * 64;
  int lr = lane >> 4, lb = lane & 15;
  f32x4 acc[4][4];
  #pragma unroll
  for(int i=0;i<4;i++)
    #pragma unroll
    for(int j=0;j<4;j++) acc[i][j] = (f32x4){0.f,0.f,0.f,0.f};

  int brow = wave*32 + (lane >> 3);
  int bcol = ((lane & 7) ^ (lane >> 3)) * 8;
  const u16t* gBh = Wth + (size_t)(n0 + brow)*512 + bcol;
  const u16t* gBl = Wtl + (size_t)(n0 + brow)*512 + bcol;
  char* lBh = Bh + wave*4096;
  char* lBl = Bl + wave*4096;
  const float* gA = X + (size_t)(row0 + wave*32 + lr)*512;
  int ac[4];
  #pragma unroll
  for(int qm = 0; qm < 4; qm++) ac[qm] = (lb ^ (lr + qm*4)) * 4;
  char* lAf = Af + wave*8192;

  for(int kt = 0; kt < 8; kt++){
    int k0 = kt * 64;
    #pragma unroll
    for(int q = 0; q < 8; q++)
      gld16(lAf + q*1024, gA + (size_t)q*4*512 + k0 + ac[q&3]);
    #pragma unroll
    for(int q = 0; q < 4; q++){
      gld16(lBh + q*1024, gBh + (size_t)q*8*512 + k0);
      if(isQ) gld16(lBl + q*1024, gBl + (size_t)q*8*512 + k0);
    }
    __syncthreads();
    #pragma unroll
    for(int kk = 0; kk < 2; kk++){
      bf16x8 ah[4], al[4], bh[4], bl[4];
      #pragma unroll
      for(int i = 0; i < 4; i++){
        int rr = wr + i*16 + lb;
        int g = kk*8 + lr*2;
        float4 x0 = *(float4*)(Af + rr*256 + ((g    ) ^ lb)*16);
        float4 x1 = *(float4*)(Af + rr*256 + ((g + 1) ^ lb)*16);
        float xs[8] = {x0.x,x0.y,x0.z,x0.w,x1.x,x1.y,x1.z,x1.w};
        #pragma unroll
        for(int e = 0; e < 8; e++){
          __bf16 hb = (__bf16)xs[e];
          ah[i][e] = hb;
          if(isQ) al[i][e] = (__bf16)(xs[e] - (float)hb);
        }
      }
      int kb = kk*64 + lr*16;
      #pragma unroll
      for(int j = 0; j < 4; j++){
        int nr = wc + j*16 + lb;
        int by = kb ^ ((nr & 7) << 4);
        bh[j] = *(bf16x8*)(Bh + nr*128 + by);
        if(isQ) bl[j] = *(bf16x8*)(Bl + nr*128 + by);
      }
      #pragma unroll
      for(int i = 0; i < 4; i++)
        #pragma unroll
        for(int j = 0; j < 4; j++){
          acc[i][j] = MFMA16(ah[i], bh[j], acc[i][j]);
          if(isQ){
            acc[i][j] = MFMA16(ah[i], bl[j], acc[i][j]);
            acc[i][j] = MFMA16(al[i], bh[j], acc[i][j]);
          }
        }
    }
    __syncthreads();
  }
  #pragma unroll
  for(int i = 0; i < 4; i++)
    #pragma unroll
    for(int j = 0; j < 4; j++){
      int colBase = wc + j*16 + lb;
      #pragma unroll
      for(int rg = 0; rg < 4; rg++){
        int row = row0 + wr + i*16 + (lr << 2) + rg;
        float val = acc[i][j][rg];
        if(isQ){
          u16t qh_, ql_; split2(val, qh_, ql_);
          size_t idx = (size_t)row*256 + (n0 + colBase);
          Qh[idx] = qh_; Ql[idx] = ql_;
        } else {
          int bb = row / 100; int tt = row - bb*100;
          int hcol = (n0 - 256) + colBase;
          Vt[((size_t)(bb*256 + hcol))*112 + tt] = f2bfu(val);
        }
      }
    }
}

// ---------------- K3: attention per batch, chunked staging (64KB LDS) -------
// 2 blocks/CU; s_setprio(1) around MFMA clusters (T5 — independent blocks at
// different phases on the same CU).
__global__ __launch_bounds__(256) void kattn(const u16t* __restrict__ Qh,
                      const u16t* __restrict__ Ql, const u16t* __restrict__ KKh,
                      const u16t* __restrict__ KKl, const u16t* __restrict__ Vt,
                      const float* __restrict__ biasArr, float* __restrict__ out){
  extern __shared__ char smem[];
  char* KH = smem;            // phase1: chunk [64][512B] swz, 32KB
  char* KL = smem + 32768;
  char* P  = smem;            // phase2: [112][256B] swz, 28672
  char* V  = smem + 28672;    // phase2: chunk [128][256B] swz, 32KB
  int b = blockIdx.x, tid = threadIdx.x, lane = tid & 63, wave = tid >> 6;

  float sc[2][7][4];

  // ---- QK^T over two K chunks ----
  for(int c = 0; c < 2; c++){
    if(c) __syncthreads();            // chunk0 reads done before restage
    int rows = c ? 48 : 64;
    for(int it = 0; it < 8; it++){
      int idx = it*256 + tid;
      if(idx < rows*32){
        int tl = idx >> 5, seg = idx & 31;
        int t = tl + c*64;
        int byte = (seg*16) ^ ((tl & 7) << 4);
        uint4 hv = {0,0,0,0}, lv = {0,0,0,0};
        if(t < 100){
          size_t g = (size_t)(b*100 + t)*256 + seg*8;
          hv = *(const uint4*)(KKh + g);
          lv = *(const uint4*)(KKl + g);
        }
        *(uint4*)(KH + tl*512 + byte) = hv;
        *(uint4*)(KL + tl*512 + byte) = lv;
      }
    }
    __syncthreads();
    int tcA = c ? 4 : 0, tcB = c ? 7 : 4;
    for(int uu = 0; uu < 2; uu++){
      if(uu == 1 && wave >= 3) continue;
      int tr = (uu == 0) ? wave : wave + 4;
      int s = tr*16 + (lane & 15);
      int gs = (s > 99) ? 99 : s;
      size_t qbase = (size_t)(b*100 + gs)*256 + (lane >> 4)*8;
      bf16x8 qh[8], ql[8];
      #pragma unroll
      for(int ks = 0; ks < 8; ks++){
        qh[ks] = *(const bf16x8*)(Qh + qbase + ks*32);
        ql[ks] = *(const bf16x8*)(Ql + qbase + ks*32);
      }
      for(int tc = tcA; tc < tcB; tc++){
        f32x4 a = (f32x4){0.f,0.f,0.f,0.f};
        int tl = tc*16 + (lane & 15) - c*64;     // local row in chunk
        __builtin_amdgcn_s_setprio(1);
        #pragma unroll
        for(int ks = 0; ks < 8; ks++){
          int kb = ks*64 + (lane >> 4)*16;
          int by = kb ^ ((tl & 7) << 4);
          bf16x8 bh = *(bf16x8*)(KH + tl*512 + by);
          bf16x8 bl = *(bf16x8*)(KL + tl*512 + by);
          a = MFMA16(qh[ks], bh, a);
          a = MFMA16(qh[ks], bl, a);
          a = MFMA16(ql[ks], bh, a);
        }
        __builtin_amdgcn_s_setprio(0);
        int t = tc*16 + (lane & 15);
        float bb = (t < 100) ? biasArr[b*112 + t] : -INFINITY;
        #pragma unroll
        for(int r = 0; r < 4; r++) sc[uu][tc][r] = a[r] + bb;
      }
    }
  }

  // ---- softmax (regs + 16-lane-group shuffles) ----
  #pragma unroll
  for(int uu = 0; uu < 2; uu++){
    if(uu == 1 && wave >= 3) continue;
    #pragma unroll
    for(int r = 0; r < 4; r++){
      float m = sc[uu][0][r];
      #pragma unroll
      for(int tc = 1; tc < 7; tc++) m = fmaxf(m, sc[uu][tc][r]);
      for(int msk = 8; msk >= 1; msk >>= 1) m = fmaxf(m, __shfl_xor(m, msk, 64));
      float ssum = 0.f;
      #pragma unroll
      for(int tc = 0; tc < 7; tc++){
        float p = expf(sc[uu][tc][r] - m);
        sc[uu][tc][r] = p; ssum += p;
      }
      for(int msk = 8; msk >= 1; msk >>= 1) ssum += __shfl_xor(ssum, msk, 64);
      float inv = 1.0f / ssum;
      #pragma unroll
      for(int tc = 0; tc < 7; tc++) sc[uu][tc][r] *= inv;
    }
  }
  __syncthreads();   // all K reads done; safe to overwrite with P/V

  // ---- write P (bf16, swizzled) + zero pad cols ----
  #pragma unroll
  for(int uu = 0; uu < 2; uu++){
    if(uu == 1 && wave >= 3) continue;
    int tr = (uu == 0) ? wave : wave + 4;
    #pragma unroll
    for(int tc = 0; tc < 7; tc++)
      #pragma unroll
      for(int r = 0; r < 4; r++){
        int srow = tr*16 + ((lane >> 4) << 2) + r;
        int t = tc*16 + (lane & 15);
        *(u16t*)(P + srow*256 + ((t*2) ^ ((srow & 7) << 4))) = f2bfu(sc[uu][tc][r]);
      }
  }
  for(int idx = tid; idx < 112*16; idx += 256){
    int srow = idx >> 4; int t = 112 + (idx & 15);
    *(u16t*)(P + srow*256 + ((t*2) ^ ((srow & 7) << 4))) = 0;
  }

  // ---- PV over two V chunks of 128 h-rows each ----
  bf16x8 pa[4];
  for(int d = 0; d < 2; d++){
    if(d) __syncthreads();             // chunk0 reads done before restage
    for(int it = 0; it < 8; it++){
      int idx = it*256 + tid;          // 128 rows * 16 segs
      int hl = idx >> 4, s16 = idx & 15; int t0 = s16*8;
      int h = d*128 + hl;
      uint4 v = {0,0,0,0};
      if(t0 < 112) v = *(const uint4*)(Vt + ((size_t)(b*256 + h))*112 + t0);
      *(uint4*)(V + hl*256 + ((t0*2) ^ ((hl & 7) << 4))) = v;
    }
    __syncthreads();
    #pragma unroll
    for(int uu = 0; uu < 2; uu++){
      if(uu == 1 && wave >= 3) continue;
      int tr = (uu == 0) ? wave : wave + 4;
      int srow = tr*16 + (lane & 15);
      #pragma unroll
      for(int ks = 0; ks < 4; ks++){
        int kb = ks*64 + (lane >> 4)*16;
        pa[ks] = *(bf16x8*)(P + srow*256 + (kb ^ ((srow & 7) << 4)));
      }
      #pragma unroll
      for(int tcl = 0; tcl < 8; tcl++){
        int tc = d*8 + tcl;
        int hl = tcl*16 + (lane & 15);       // local V row
        f32x4 a = (f32x4){0.f,0.f,0.f,0.f};
        __builtin_amdgcn_s_setprio(1);
        #pragma unroll
        for(int ks = 0; ks < 4; ks++){
          int kb = ks*64 + (lane >> 4)*16;
          bf16x8 vb = *(bf16x8*)(V + hl*256 + (kb ^ ((hl & 7) << 4)));
          a = MFMA16(pa[ks], vb, a);
        }
        __builtin_amdgcn_s_setprio(0);
        #pragma unroll
        for(int r = 0; r < 4; r++){
          int so = tr*16 + ((lane >> 4) << 2) + r;
          if(so < 100)
            out[((size_t)(b*100 + so))*768 + 512 + tc*16 + (lane & 15)] = a[r];
        }
      }
    }
  }
}

extern "C" void kernel_launch(void* const* d_in, const int* in_sizes, int n_in,
                              void* d_out, int out_size, void* d_ws, size_t ws_size,
                              hipStream_t stream) {
  const float* X     = (const float*)d_in[0];
  const int*   masks = (const int*)d_in[1];
  const float* Wq    = (const float*)d_in[2];
  const float* Wv    = (const float*)d_in[3];
  const float* u     = (const float*)d_in[4];
  const float* v     = (const float*)d_in[5];
  float* out = (float*)d_out;
  char* ws = (char*)d_ws;

  // Big layout needs Xh/Xl (100 MB each).
  const size_t NEED_BIG = 479760896ULL;
  bool big = (ws_size >= NEED_BIG);

  size_t o = 0;
  auto alloc = [&](size_t n){ size_t r = o; o += (n + 255) & ~(size_t)255; return r; };
  u16t*  Qh      = (u16t*)(ws + alloc(52428800));    // 102400 x 256 bf16
  u16t*  Ql      = (u16t*)(ws + alloc(52428800));
  u16t*  KKh     = (u16t*)(ws + alloc(52428800));
  u16t*  KKl     = (u16t*)(ws + alloc(52428800));
  u16t*  Vt      = (u16t*)(ws + alloc(58720256));    // 1024 x 256 x 112 bf16
  u16t*  Wth     = (u16t*)(ws + alloc(524288));      // 512 x 512 bf16
  u16t*  Wtl     = (u16t*)(ws + alloc(524288));
  float* posS    = (float*)(ws + alloc(102400));     // 100 x 256 f32
  float* posbias = (float*)(ws + alloc(512));        // 100 f32
  float* biasArr = (float*)(ws + alloc(458752));     // 1024 x 112 f32
  u16t*  Xh      = nullptr; u16t* Xl = nullptr;
  if(big){
    Xh = (u16t*)(ws + alloc(104857600));             // 102400 x 512 bf16
    Xl = (u16t*)(ws + alloc(104857600));
  }

  hipFuncSetAttribute((const void*)kgemm_bf,  hipFuncAttributeMaxDynamicSharedMemorySize, 65536);
  hipFuncSetAttribute((const void*)kgemm_f32, hipFuncAttributeMaxDynamicSharedMemorySize, 65536);
  hipFuncSetAttribute((const void*)kattn,     hipFuncAttributeMaxDynamicSharedMemorySize, 65536);

  kposw<<<1124, 256, 0, stream>>>(v, Wq, Wv, posS, posbias, Wth, Wtl);
  kprep<<<25600, 256, 0, stream>>>(X, masks, u, posS, posbias, out, KKh, KKl,
                                   Xh, Xl, biasArr, big ? 1 : 0);
  if(big)
    kgemm_bf<<<3200, 256, 65536, stream>>>(Xh, Xl, Wth, Wtl, Qh, Ql, Vt);
  else
    kgemm_f32<<<3200, 256, 65536, stream>>>(X, Wth, Wtl, Qh, Ql, Vt);
  kattn<<<1024, 256, 65536, stream>>>(Qh, Ql, KKh, KKl, Vt, biasArr, out);
}